// Round 1
// baseline (165.885 us; speedup 1.0000x reference)
//
#include <hip/hip_runtime.h>

// RFA: q,k,v = x@W^T+b ; phi = relu((x/||x||) @ (scale*rp0)^T)/8 ;
// causal linear attention (inclusive) ; out = h @ Wo^T + bo
// B=2 L=1024 DIM=1024 H=16 D=64 PHI=64

typedef unsigned short ushort_t;
typedef __attribute__((ext_vector_type(8))) __bf16 bf16x8;
typedef __attribute__((ext_vector_type(4))) float f32x4;

#define MLS -11.512925464970229f  // log(1e-5)

__device__ __forceinline__ ushort_t f2b(float f) {
  union { float f; unsigned u; } v; v.f = f;
  unsigned r = v.u + 0x7FFFu + ((v.u >> 16) & 1u);  // RNE
  return (ushort_t)(r >> 16);
}

__device__ __forceinline__ void gload16(const void* g, void* l) {
  __builtin_amdgcn_global_load_lds((__attribute__((address_space(1))) void*)(void*)g,
                                   (__attribute__((address_space(3))) void*)l, 16, 0, 0);
}

__device__ __forceinline__ f32x4 mfma_bf16(bf16x8 a, bf16x8 b, f32x4 c) {
  return __builtin_amdgcn_mfma_f32_16x16x32_bf16(a, b, c, 0, 0, 0);
}

// ---------------- K0: f32 -> bf16 conversions ----------------
__global__ __launch_bounds__(256) void convert_kernel(
    const float* __restrict__ x, const float* __restrict__ Wq, const float* __restrict__ Wk,
    const float* __restrict__ Wv, const float* __restrict__ Wo,
    const float* __restrict__ bq, const float* __restrict__ bk, const float* __restrict__ bv,
    ushort_t* __restrict__ xb, ushort_t* __restrict__ Wcat, ushort_t* __restrict__ Wob,
    float* __restrict__ bcat) {
  const size_t NX = 2u*1024u*1024u, NW = 1024u*1024u;
  const size_t total = NX + 4*NW + 3072;
  for (size_t i = (size_t)blockIdx.x*256 + threadIdx.x; i < total; i += (size_t)gridDim.x*256) {
    if (i < NX) { xb[i] = f2b(x[i]); }
    else if (i < NX + NW)   { size_t j = i - NX;      Wcat[j]        = f2b(Wq[j]); }
    else if (i < NX + 2*NW) { size_t j = i - NX - NW; Wcat[j + NW]   = f2b(Wk[j]); }
    else if (i < NX + 3*NW) { size_t j = i - NX - 2*NW; Wcat[j + 2*NW] = f2b(Wv[j]); }
    else if (i < NX + 4*NW) { size_t j = i - NX - 3*NW; Wob[j] = f2b(Wo[j]); }
    else {
      size_t j = i - NX - 4*NW;
      bcat[j] = (j < 1024) ? bq[j] : (j < 2048 ? bk[j - 1024] : bv[j - 2048]);
    }
  }
}

// ---------------- GEMM: C[M,N] = A[M,K] @ B[N,K]^T + bias[N] ----------------
// bf16 inputs, f32 out. 128x128 tile, BK=32, 4 waves (2x2 of 64x64).
__global__ __launch_bounds__(256) void gemm_bt(
    const ushort_t* __restrict__ A, const ushort_t* __restrict__ Bm,
    const float* __restrict__ bias, float* __restrict__ C, int M, int N, int K) {
  __shared__ __align__(16) ushort_t As[128*32];
  __shared__ __align__(16) ushort_t Bs[128*32];
  int nb = N >> 7;
  int bx = blockIdx.x % nb, by = blockIdx.x / nb;
  int m0 = by << 7, n0 = bx << 7;
  int tid = threadIdx.x;
  int w = tid >> 6, l = tid & 63;
  int wm = (w >> 1) << 6, wn = (w & 1) << 6;
  int lr = l & 15, lg = l >> 4;
  f32x4 acc[4][4] = {};
  for (int k0 = 0; k0 < K; k0 += 32) {
#pragma unroll
    for (int it = 0; it < 2; ++it) {
      int idx = it*256 + tid;           // 16B chunk id, 512 per tile
      int row = idx >> 2, cg = idx & 3;
      gload16(A  + (size_t)(m0 + row)*K + k0 + cg*8, As + idx*8);
      gload16(Bm + (size_t)(n0 + row)*K + k0 + cg*8, Bs + idx*8);
    }
    __syncthreads();
    bf16x8 af[4], bf[4];
#pragma unroll
    for (int i = 0; i < 4; ++i) af[i] = *(const bf16x8*)(As + (wm + i*16 + lr)*32 + lg*8);
#pragma unroll
    for (int i = 0; i < 4; ++i) bf[i] = *(const bf16x8*)(Bs + (wn + i*16 + lr)*32 + lg*8);
#pragma unroll
    for (int mi = 0; mi < 4; ++mi)
#pragma unroll
      for (int ni = 0; ni < 4; ++ni)
        acc[mi][ni] = mfma_bf16(af[mi], bf[ni], acc[mi][ni]);
    __syncthreads();
  }
#pragma unroll
  for (int mi = 0; mi < 4; ++mi) {
    int row = m0 + wm + mi*16 + lg*4;
#pragma unroll
    for (int ni = 0; ni < 4; ++ni) {
      int col = n0 + wn + ni*16 + lr;
      float bv = bias[col];
#pragma unroll
      for (int r = 0; r < 4; ++r)
        C[(size_t)(row + r)*N + col] = acc[mi][ni][r] + bv;
    }
  }
}

// ---------------- K2: phi + v transpose ----------------
// wave handles one (b,t,h): lane = d. Writes phiq/phik [bh][t][p] (chunk-swizzled by t&7),
// vbT [bh][d][t] (within-128-tile chunk-swizzled by d&15). All bf16.
__global__ __launch_bounds__(256) void phi_kernel(
    const float* __restrict__ qkv, const float* __restrict__ lsig, const float* __restrict__ rp0,
    ushort_t* __restrict__ phiq, ushort_t* __restrict__ phik, ushort_t* __restrict__ vbT) {
  __shared__ float rpT[64*64];   // rpT[d][p] = rp0[p][d]
  for (int i = threadIdx.x; i < 4096; i += 256) {
    int p = i >> 6, d = i & 63;
    rpT[d*64 + p] = rp0[i];
  }
  __syncthreads();
  int w = threadIdx.x >> 6, l = threadIdx.x & 63;
  int gw = blockIdx.x*4 + w, nw = gridDim.x*4;
  for (int task = gw; task < 2*1024*16; task += nw) {
    int t = task & 1023, bh = task >> 10;
    int b = bh >> 4, h = bh & 15;
    const float* base = qkv + ((size_t)(b*1024 + t))*3072 + h*64;
    float qd = base[l], kd = base[1024 + l], vv = base[2048 + l];
    float nq = qd*qd, nk = kd*kd;
#pragma unroll
    for (int s = 1; s < 64; s <<= 1) { nq += __shfl_xor(nq, s); nk += __shfl_xor(nk, s); }
    float rq = 1.f / fmaxf(sqrtf(nq), 1e-12f);
    float rk = 1.f / fmaxf(sqrtf(nk), 1e-12f);
    float sc = expf(fmaxf(lsig[h*64 + l], MLS));
    float yq = qd * rq * sc, yk = kd * rk * sc;
    float aq = 0.f, ak = 0.f;
#pragma unroll
    for (int d0 = 0; d0 < 64; ++d0) {
      float byq = __shfl(yq, d0), byk = __shfl(yk, d0);
      float rr = rpT[d0*64 + l];
      aq = fmaf(byq, rr, aq);
      ak = fmaf(byk, rr, ak);
    }
    aq = fmaxf(aq, 0.f) * 0.125f;
    ak = fmaxf(ak, 0.f) * 0.125f;
    size_t obase = ((size_t)bh << 16) + (size_t)t*64;
    int sp = (l & 7) | ((((l >> 3) ^ (t & 7)) & 7) << 3);   // lane = p here
    phiq[obase + sp] = f2b(aq);
    phik[obase + sp] = f2b(ak);
    int lloc = t & 127;
    int sv = (lloc & 7) | ((((lloc >> 3) ^ (l & 15)) & 15) << 3);  // lane = d here
    vbT[((size_t)bh << 16) + (size_t)l*1024 + (t >> 7)*128 + sv] = f2b(vv);
  }
}

// ---------------- K3: causal linear attention ----------------
// block = (bh, qtile of 128). 4 waves, each owns 32 q rows and all 128 keys per tile.
// Swapped QK^T (scores [key][q]) so P packs into ds_write_b64; P stored [q][key] XOR-swizzled.
__global__ __launch_bounds__(256) void attn_kernel(
    const ushort_t* __restrict__ phiq, const ushort_t* __restrict__ phik,
    const ushort_t* __restrict__ vbT, ushort_t* __restrict__ hb) {
  __shared__ __align__(16) ushort_t Qs[128*64];
  __shared__ __align__(16) ushort_t Ks[128*64];
  __shared__ __align__(16) ushort_t Vs[64*128];
  __shared__ __align__(16) ushort_t Ps[128*128];
  __shared__ float den_lds[128];
  int blk = blockIdx.x;
  int qt = blk & 7, bh = blk >> 3;
  int b = bh >> 4, h = bh & 15;
  int tid = threadIdx.x, w = tid >> 6, l = tid & 63;
  int lr = l & 15, lg = l >> 4;
  const ushort_t* pq = phiq + ((size_t)bh << 16) + qt*8192;
  const ushort_t* pk = phik + ((size_t)bh << 16);
  const ushort_t* pv = vbT  + ((size_t)bh << 16);
#pragma unroll
  for (int it = 0; it < 4; ++it) {
    int idx = it*256 + tid;
    gload16(pq + idx*8, Qs + idx*8);
  }
  f32x4 nacc[2][4] = {};
  float den[2] = {0.f, 0.f};
  for (int kt = 0; kt <= qt; ++kt) {
#pragma unroll
    for (int it = 0; it < 4; ++it) {
      int idx = it*256 + tid;
      gload16(pk + kt*8192 + idx*8, Ks + idx*8);
      gload16(pv + (idx >> 4)*1024 + kt*128 + (idx & 15)*8, Vs + idx*8);
    }
    __syncthreads();
    // ---- QK^T swapped: scores s[key][q] ----
    bf16x8 qf[2][2];
#pragma unroll
    for (int qi = 0; qi < 2; ++qi)
#pragma unroll
      for (int ks = 0; ks < 2; ++ks) {
        int q = w*32 + qi*16 + lr;
        qf[qi][ks] = *(const bf16x8*)(Qs + q*64 + (((ks*4 + lg) ^ (q & 7)) << 3));
      }
    f32x4 sfr[8][2] = {};
#pragma unroll
    for (int kf = 0; kf < 8; ++kf) {
#pragma unroll
      for (int ks = 0; ks < 2; ++ks) {
        int kloc = kf*16 + lr;
        bf16x8 af = *(const bf16x8*)(Ks + kloc*64 + (((ks*4 + lg) ^ (kloc & 7)) << 3));
        sfr[kf][0] = mfma_bf16(af, qf[0][ks], sfr[kf][0]);
        sfr[kf][1] = mfma_bf16(af, qf[1][ks], sfr[kf][1]);
      }
    }
    // ---- mask (diag tile), den, pack P to LDS ----
    bool diag = (kt == qt);
#pragma unroll
    for (int kf = 0; kf < 8; ++kf) {
#pragma unroll
      for (int qi = 0; qi < 2; ++qi) {
        int q = w*32 + qi*16 + lr;
        f32x4 v4 = sfr[kf][qi];
        if (diag) {
          int keyb = kf*16 + lg*4;
#pragma unroll
          for (int r = 0; r < 4; ++r)
            if (keyb + r > q) v4[r] = 0.f;
        }
        den[qi] += v4[0] + v4[1] + v4[2] + v4[3];
        unsigned long long u = (unsigned long long)f2b(v4[0])
                             | ((unsigned long long)f2b(v4[1]) << 16)
                             | ((unsigned long long)f2b(v4[2]) << 32)
                             | ((unsigned long long)f2b(v4[3]) << 48);
        int chunk = (2*kf + (lg >> 1)) ^ (q & 7);
        *(unsigned long long*)(Ps + q*128 + chunk*8 + (lg & 1)*4) = u;
      }
    }
    __syncthreads();
    // ---- PV: num[q][d] += P[q][key] * V[key][d] ----
#pragma unroll
    for (int ks = 0; ks < 4; ++ks) {
      bf16x8 pa[2];
#pragma unroll
      for (int qi = 0; qi < 2; ++qi) {
        int q = w*32 + qi*16 + lr;
        pa[qi] = *(const bf16x8*)(Ps + q*128 + (((4*ks + lg) ^ (q & 7)) << 3));
      }
#pragma unroll
      for (int df = 0; df < 4; ++df) {
        int d = df*16 + lr;
        bf16x8 vf = *(const bf16x8*)(Vs + d*128 + (((4*ks + lg) ^ (d & 15)) << 3));
        nacc[0][df] = mfma_bf16(pa[0], vf, nacc[0][df]);
        nacc[1][df] = mfma_bf16(pa[1], vf, nacc[1][df]);
      }
    }
    __syncthreads();
  }
  // den: reduce over the 4 lane-groups (bits 4,5)
  den[0] += __shfl_xor(den[0], 16); den[0] += __shfl_xor(den[0], 32);
  den[1] += __shfl_xor(den[1], 16); den[1] += __shfl_xor(den[1], 32);
  if (lg == 0) {
    den_lds[w*32 + lr]      = den[0];
    den_lds[w*32 + 16 + lr] = den[1];
  }
  __syncthreads();
#pragma unroll
  for (int qi = 0; qi < 2; ++qi)
#pragma unroll
    for (int df = 0; df < 4; ++df)
#pragma unroll
      for (int r = 0; r < 4; ++r) {
        int qloc = w*32 + qi*16 + lg*4 + r;
        int d = df*16 + lr;
        float dd = fmaxf(den_lds[qloc], 1e-5f);
        float val = nacc[qi][df][r] / dd;
        hb[((size_t)(b*1024 + qt*128 + qloc))*1024 + h*64 + d] = f2b(val);
      }
}

// ---------------- launch ----------------
extern "C" void kernel_launch(void* const* d_in, const int* in_sizes, int n_in,
                              void* d_out, int out_size, void* d_ws, size_t ws_size,
                              hipStream_t stream) {
  const float* x  = (const float*)d_in[0];
  // d_in[1] = mask (all ones in this problem) -- unused
  const float* Wq = (const float*)d_in[2];
  const float* bq = (const float*)d_in[3];
  const float* Wk = (const float*)d_in[4];
  const float* bk = (const float*)d_in[5];
  const float* Wv = (const float*)d_in[6];
  const float* bv = (const float*)d_in[7];
  const float* Wo = (const float*)d_in[8];
  const float* bo = (const float*)d_in[9];
  const float* ls = (const float*)d_in[10];
  const float* rp = (const float*)d_in[11];

  char* ws = (char*)d_ws;
  size_t off = 0;
  auto alloc = [&](size_t bytes) { char* p = ws + off; off += (bytes + 255) & ~(size_t)255; return p; };
  ushort_t* xb   = (ushort_t*)alloc((size_t)2048*1024*2);
  ushort_t* Wcat = (ushort_t*)alloc((size_t)3072*1024*2);
  ushort_t* Wob  = (ushort_t*)alloc((size_t)1024*1024*2);
  float*    bcat = (float*)   alloc((size_t)3072*4);
  float*    qkv  = (float*)   alloc((size_t)2048*3072*4);
  ushort_t* phiq = (ushort_t*)alloc((size_t)32*1024*64*2);
  ushort_t* phik = (ushort_t*)alloc((size_t)32*1024*64*2);
  ushort_t* vbT  = (ushort_t*)alloc((size_t)32*64*1024*2);
  ushort_t* hb   = (ushort_t*)alloc((size_t)2048*1024*2);

  convert_kernel<<<2048, 256, 0, stream>>>(x, Wq, Wk, Wv, Wo, bq, bk, bv, xb, Wcat, Wob, bcat);
  gemm_bt<<<16*24, 256, 0, stream>>>(xb, Wcat, bcat, qkv, 2048, 3072, 1024);
  phi_kernel<<<2048, 256, 0, stream>>>(qkv, ls, rp, phiq, phik, vbT);
  attn_kernel<<<256, 256, 0, stream>>>(phiq, phik, vbT, hb);
  gemm_bt<<<16*8, 256, 0, stream>>>(hb, Wob, bo, (float*)d_out, 2048, 1024, 1024);
}

// Round 2
// 113.151 us; speedup vs baseline: 1.4661x; 1.4661x over previous
//
#include <hip/hip_runtime.h>

// RFA: q,k,v = x@W^T+b ; phi = relu((x/||x||) @ (scale*rp0)^T)/8 ;
// causal linear attention (inclusive) ; out = h @ Wo^T + bo
// B=2 L=1024 DIM=1024 H=16 D=64 PHI=64

typedef unsigned short ushort_t;
typedef __attribute__((ext_vector_type(8))) __bf16 bf16x8;
typedef __attribute__((ext_vector_type(4))) float f32x4;

#define MLS -11.512925464970229f  // log(1e-5)

__device__ __forceinline__ ushort_t f2b(float f) {
  union { float f; unsigned u; } v; v.f = f;
  unsigned r = v.u + 0x7FFFu + ((v.u >> 16) & 1u);  // RNE
  return (ushort_t)(r >> 16);
}

__device__ __forceinline__ void gload16(const void* g, void* l) {
  __builtin_amdgcn_global_load_lds((__attribute__((address_space(1))) void*)(void*)g,
                                   (__attribute__((address_space(3))) void*)l, 16, 0, 0);
}

__device__ __forceinline__ f32x4 mfma_bf16(bf16x8 a, bf16x8 b, f32x4 c) {
  return __builtin_amdgcn_mfma_f32_16x16x32_bf16(a, b, c, 0, 0, 0);
}

// ---------------- K0: f32 -> bf16 conversions ----------------
__global__ __launch_bounds__(256) void convert_kernel(
    const float* __restrict__ x, const float* __restrict__ Wq, const float* __restrict__ Wk,
    const float* __restrict__ Wv, const float* __restrict__ Wo,
    const float* __restrict__ bq, const float* __restrict__ bk, const float* __restrict__ bv,
    ushort_t* __restrict__ xb, ushort_t* __restrict__ Wcat, ushort_t* __restrict__ Wob,
    float* __restrict__ bcat) {
  const size_t NX = 2u*1024u*1024u, NW = 1024u*1024u;
  const size_t total = NX + 4*NW + 3072;
  for (size_t i = (size_t)blockIdx.x*256 + threadIdx.x; i < total; i += (size_t)gridDim.x*256) {
    if (i < NX) { xb[i] = f2b(x[i]); }
    else if (i < NX + NW)   { size_t j = i - NX;      Wcat[j]        = f2b(Wq[j]); }
    else if (i < NX + 2*NW) { size_t j = i - NX - NW; Wcat[j + NW]   = f2b(Wk[j]); }
    else if (i < NX + 3*NW) { size_t j = i - NX - 2*NW; Wcat[j + 2*NW] = f2b(Wv[j]); }
    else if (i < NX + 4*NW) { size_t j = i - NX - 3*NW; Wob[j] = f2b(Wo[j]); }
    else {
      size_t j = i - NX - 4*NW;
      bcat[j] = (j < 1024) ? bq[j] : (j < 2048 ? bk[j - 1024] : bv[j - 2048]);
    }
  }
}

// ---------------- GEMM: C[M,N] = A[M,K] @ B[N,K]^T + bias[N] ----------------
// bf16 inputs, f32 out. 128x128 tile, BK=32, 4 waves (2x2 of 64x64).
__global__ __launch_bounds__(256) void gemm_bt(
    const ushort_t* __restrict__ A, const ushort_t* __restrict__ Bm,
    const float* __restrict__ bias, float* __restrict__ C, int M, int N, int K) {
  __shared__ __align__(16) ushort_t As[128*32];
  __shared__ __align__(16) ushort_t Bs[128*32];
  int nb = N >> 7;
  int bx = blockIdx.x % nb, by = blockIdx.x / nb;
  int m0 = by << 7, n0 = bx << 7;
  int tid = threadIdx.x;
  int w = tid >> 6, l = tid & 63;
  int wm = (w >> 1) << 6, wn = (w & 1) << 6;
  int lr = l & 15, lg = l >> 4;
  f32x4 acc[4][4] = {};
  for (int k0 = 0; k0 < K; k0 += 32) {
#pragma unroll
    for (int it = 0; it < 2; ++it) {
      int idx = it*256 + tid;           // 16B chunk id, 512 per tile
      int row = idx >> 2, cg = idx & 3;
      gload16(A  + (size_t)(m0 + row)*K + k0 + cg*8, As + idx*8);
      gload16(Bm + (size_t)(n0 + row)*K + k0 + cg*8, Bs + idx*8);
    }
    __syncthreads();
    bf16x8 af[4], bf[4];
#pragma unroll
    for (int i = 0; i < 4; ++i) af[i] = *(const bf16x8*)(As + (wm + i*16 + lr)*32 + lg*8);
#pragma unroll
    for (int i = 0; i < 4; ++i) bf[i] = *(const bf16x8*)(Bs + (wn + i*16 + lr)*32 + lg*8);
#pragma unroll
    for (int mi = 0; mi < 4; ++mi)
#pragma unroll
      for (int ni = 0; ni < 4; ++ni)
        acc[mi][ni] = mfma_bf16(af[mi], bf[ni], acc[mi][ni]);
    __syncthreads();
  }
#pragma unroll
  for (int mi = 0; mi < 4; ++mi) {
    int row = m0 + wm + mi*16 + lg*4;
#pragma unroll
    for (int ni = 0; ni < 4; ++ni) {
      int col = n0 + wn + ni*16 + lr;
      float bv = bias[col];
#pragma unroll
      for (int r = 0; r < 4; ++r)
        C[(size_t)(row + r)*N + col] = acc[mi][ni][r] + bv;
    }
  }
}

// ---------------- K2: phi via MFMA + v transpose ----------------
// block = 64 tokens x one (b,h). Phase 1: normalize+scale q,k (4 thr/token) -> bf16 LDS
// (XOR-swizzled rows). Phase 2: waves 0-1 compute phiq = relu(Yq @ rp0^T)/8 via MFMA,
// waves 2-3 phik. Writes phi pre-swizzled global layout; v transposed as side loop.
__global__ __launch_bounds__(256) void phi_kernel(
    const float* __restrict__ qkv, const float* __restrict__ lsig, const float* __restrict__ rp0,
    ushort_t* __restrict__ phiq, ushort_t* __restrict__ phik, ushort_t* __restrict__ vbT) {
  __shared__ float scl[64];
  __shared__ __align__(16) ushort_t Rs[64*64];   // rp0 bf16 [p][d], chunk^= p&7
  __shared__ __align__(16) ushort_t Yq[64*64];   // [t][d], chunk ^= t&7
  __shared__ __align__(16) ushort_t Yk[64*64];
  int tid = threadIdx.x;
  int tt = blockIdx.x & 15, bh = blockIdx.x >> 4;
  int b = bh >> 4, h = bh & 15;
  int t0 = tt * 64;
  if (tid < 64) scl[tid] = expf(fmaxf(lsig[h*64 + tid], MLS));
  for (int i = tid; i < 4096; i += 256) {
    int p = i >> 6, d = i & 63;
    int c = (d >> 3) ^ (p & 7);
    Rs[p*64 + c*8 + (d & 7)] = f2b(rp0[i]);
  }
  __syncthreads();
  // phase 1: 4 threads per token; each handles 16 of the 64 dims
  {
    int r = tid >> 2, q4 = tid & 3;
    const float* rowb = qkv + ((size_t)(b*1024 + t0 + r))*3072 + h*64 + q4*16;
    const float* sclp = scl + q4*16;
#pragma unroll
    for (int mat = 0; mat < 2; ++mat) {  // 0 = q, 1 = k
      const float* src = rowb + mat*1024;
      ushort_t* dst = mat ? Yk : Yq;
      float4 xv[4];
#pragma unroll
      for (int j = 0; j < 4; ++j) xv[j] = *(const float4*)(src + j*4);
      float ss = 0.f;
#pragma unroll
      for (int j = 0; j < 4; ++j)
        ss += xv[j].x*xv[j].x + xv[j].y*xv[j].y + xv[j].z*xv[j].z + xv[j].w*xv[j].w;
      ss += __shfl_xor(ss, 1); ss += __shfl_xor(ss, 2);
      float rinv = 1.f / fmaxf(sqrtf(ss), 1e-12f);
      float yv[16];
#pragma unroll
      for (int j = 0; j < 4; ++j) {
        yv[j*4+0] = xv[j].x * rinv * sclp[j*4+0];
        yv[j*4+1] = xv[j].y * rinv * sclp[j*4+1];
        yv[j*4+2] = xv[j].z * rinv * sclp[j*4+2];
        yv[j*4+3] = xv[j].w * rinv * sclp[j*4+3];
      }
#pragma unroll
      for (int hf = 0; hf < 2; ++hf) {
        uint4 u;
        u.x = (unsigned)f2b(yv[hf*8+0]) | ((unsigned)f2b(yv[hf*8+1]) << 16);
        u.y = (unsigned)f2b(yv[hf*8+2]) | ((unsigned)f2b(yv[hf*8+3]) << 16);
        u.z = (unsigned)f2b(yv[hf*8+4]) | ((unsigned)f2b(yv[hf*8+5]) << 16);
        u.w = (unsigned)f2b(yv[hf*8+6]) | ((unsigned)f2b(yv[hf*8+7]) << 16);
        *(uint4*)(dst + r*64 + (((q4*2 + hf) ^ (r & 7)) << 3)) = u;
      }
    }
  }
  // v transpose: wave w handles 16 tokens, lane = d
  {
    int w = tid >> 6, l = tid & 63;
#pragma unroll
    for (int i = 0; i < 16; ++i) {
      int tg = t0 + w*16 + i;
      float vv = qkv[((size_t)(b*1024 + tg))*3072 + 2048 + h*64 + l];
      int lloc = tg & 127;
      int sv = (lloc & 7) | ((((lloc >> 3) ^ (l & 15)) & 15) << 3);
      vbT[((size_t)bh << 16) + (size_t)l*1024 + (tg >> 7)*128 + sv] = f2b(vv);
    }
  }
  __syncthreads();
  // phase 2: MFMA  out[t][p] = Y[t][:] . rp0[p][:]
  {
    int w = tid >> 6, l = tid & 63, lr = l & 15, lg = l >> 4;
    const ushort_t* Y = (w < 2) ? Yq : Yk;
    ushort_t* dst = (w < 2) ? phiq : phik;
    int row0 = (w & 1) * 32;
    f32x4 acc[2][4] = {};
#pragma unroll
    for (int kk = 0; kk < 2; ++kk) {
      bf16x8 af[2], bfr[4];
#pragma unroll
      for (int mi = 0; mi < 2; ++mi) {
        int rrow = row0 + mi*16 + lr;
        af[mi] = *(const bf16x8*)(Y + rrow*64 + (((kk*4 + lg) ^ (rrow & 7)) << 3));
      }
#pragma unroll
      for (int ni = 0; ni < 4; ++ni) {
        int p = ni*16 + lr;
        bfr[ni] = *(const bf16x8*)(Rs + p*64 + (((kk*4 + lg) ^ (p & 7)) << 3));
      }
#pragma unroll
      for (int mi = 0; mi < 2; ++mi)
#pragma unroll
        for (int ni = 0; ni < 4; ++ni)
          acc[mi][ni] = mfma_bf16(af[mi], bfr[ni], acc[mi][ni]);
    }
#pragma unroll
    for (int mi = 0; mi < 2; ++mi)
#pragma unroll
      for (int ni = 0; ni < 4; ++ni)
#pragma unroll
        for (int r = 0; r < 4; ++r) {
          int tg = t0 + row0 + mi*16 + lg*4 + r;
          int p = ni*16 + lr;
          float val = fmaxf(acc[mi][ni][r], 0.f) * 0.125f;
          int sp = (p & 7) | ((((p >> 3) ^ (tg & 7)) & 7) << 3);
          dst[((size_t)bh << 16) + (size_t)tg*64 + sp] = f2b(val);
        }
  }
}

// ---------------- K3: causal linear attention ----------------
// block = (bh, qtile of 128). 4 waves, each owns 32 q rows and all 128 keys per tile.
// Swapped QK^T (scores [key][q]) so P packs into ds_write_b64; P stored [q][key] XOR-swizzled.
__global__ __launch_bounds__(256) void attn_kernel(
    const ushort_t* __restrict__ phiq, const ushort_t* __restrict__ phik,
    const ushort_t* __restrict__ vbT, ushort_t* __restrict__ hb) {
  __shared__ __align__(16) ushort_t Qs[128*64];
  __shared__ __align__(16) ushort_t Ks[128*64];
  __shared__ __align__(16) ushort_t Vs[64*128];
  __shared__ __align__(16) ushort_t Ps[128*128];
  __shared__ float den_lds[128];
  int blk = blockIdx.x;
  int qt = blk & 7, bh = blk >> 3;
  int b = bh >> 4, h = bh & 15;
  int tid = threadIdx.x, w = tid >> 6, l = tid & 63;
  int lr = l & 15, lg = l >> 4;
  const ushort_t* pq = phiq + ((size_t)bh << 16) + qt*8192;
  const ushort_t* pk = phik + ((size_t)bh << 16);
  const ushort_t* pv = vbT  + ((size_t)bh << 16);
#pragma unroll
  for (int it = 0; it < 4; ++it) {
    int idx = it*256 + tid;
    gload16(pq + idx*8, Qs + idx*8);
  }
  f32x4 nacc[2][4] = {};
  float den[2] = {0.f, 0.f};
  for (int kt = 0; kt <= qt; ++kt) {
#pragma unroll
    for (int it = 0; it < 4; ++it) {
      int idx = it*256 + tid;
      gload16(pk + kt*8192 + idx*8, Ks + idx*8);
      gload16(pv + (idx >> 4)*1024 + kt*128 + (idx & 15)*8, Vs + idx*8);
    }
    __syncthreads();
    // ---- QK^T swapped: scores s[key][q] ----
    bf16x8 qf[2][2];
#pragma unroll
    for (int qi = 0; qi < 2; ++qi)
#pragma unroll
      for (int ks = 0; ks < 2; ++ks) {
        int q = w*32 + qi*16 + lr;
        qf[qi][ks] = *(const bf16x8*)(Qs + q*64 + (((ks*4 + lg) ^ (q & 7)) << 3));
      }
    f32x4 sfr[8][2] = {};
#pragma unroll
    for (int kf = 0; kf < 8; ++kf) {
#pragma unroll
      for (int ks = 0; ks < 2; ++ks) {
        int kloc = kf*16 + lr;
        bf16x8 af = *(const bf16x8*)(Ks + kloc*64 + (((ks*4 + lg) ^ (kloc & 7)) << 3));
        sfr[kf][0] = mfma_bf16(af, qf[0][ks], sfr[kf][0]);
        sfr[kf][1] = mfma_bf16(af, qf[1][ks], sfr[kf][1]);
      }
    }
    // ---- mask (diag tile), den, pack P to LDS ----
    bool diag = (kt == qt);
#pragma unroll
    for (int kf = 0; kf < 8; ++kf) {
#pragma unroll
      for (int qi = 0; qi < 2; ++qi) {
        int q = w*32 + qi*16 + lr;
        f32x4 v4 = sfr[kf][qi];
        if (diag) {
          int keyb = kf*16 + lg*4;
#pragma unroll
          for (int r = 0; r < 4; ++r)
            if (keyb + r > q) v4[r] = 0.f;
        }
        den[qi] += v4[0] + v4[1] + v4[2] + v4[3];
        unsigned long long u = (unsigned long long)f2b(v4[0])
                             | ((unsigned long long)f2b(v4[1]) << 16)
                             | ((unsigned long long)f2b(v4[2]) << 32)
                             | ((unsigned long long)f2b(v4[3]) << 48);
        int chunk = (2*kf + (lg >> 1)) ^ (q & 7);
        *(unsigned long long*)(Ps + q*128 + chunk*8 + (lg & 1)*4) = u;
      }
    }
    __syncthreads();
    // ---- PV: num[q][d] += P[q][key] * V[key][d] ----
#pragma unroll
    for (int ks = 0; ks < 4; ++ks) {
      bf16x8 pa[2];
#pragma unroll
      for (int qi = 0; qi < 2; ++qi) {
        int q = w*32 + qi*16 + lr;
        pa[qi] = *(const bf16x8*)(Ps + q*128 + (((4*ks + lg) ^ (q & 7)) << 3));
      }
#pragma unroll
      for (int df = 0; df < 4; ++df) {
        int d = df*16 + lr;
        bf16x8 vf = *(const bf16x8*)(Vs + d*128 + (((4*ks + lg) ^ (d & 15)) << 3));
        nacc[0][df] = mfma_bf16(pa[0], vf, nacc[0][df]);
        nacc[1][df] = mfma_bf16(pa[1], vf, nacc[1][df]);
      }
    }
    __syncthreads();
  }
  // den: reduce over the 4 lane-groups (bits 4,5)
  den[0] += __shfl_xor(den[0], 16); den[0] += __shfl_xor(den[0], 32);
  den[1] += __shfl_xor(den[1], 16); den[1] += __shfl_xor(den[1], 32);
  if (lg == 0) {
    den_lds[w*32 + lr]      = den[0];
    den_lds[w*32 + 16 + lr] = den[1];
  }
  __syncthreads();
#pragma unroll
  for (int qi = 0; qi < 2; ++qi)
#pragma unroll
    for (int df = 0; df < 4; ++df)
#pragma unroll
      for (int r = 0; r < 4; ++r) {
        int qloc = w*32 + qi*16 + lg*4 + r;
        int d = df*16 + lr;
        float dd = fmaxf(den_lds[qloc], 1e-5f);
        float val = nacc[qi][df][r] / dd;
        hb[((size_t)(b*1024 + qt*128 + qloc))*1024 + h*64 + d] = f2b(val);
      }
}

// ---------------- launch ----------------
extern "C" void kernel_launch(void* const* d_in, const int* in_sizes, int n_in,
                              void* d_out, int out_size, void* d_ws, size_t ws_size,
                              hipStream_t stream) {
  const float* x  = (const float*)d_in[0];
  // d_in[1] = mask (all ones in this problem) -- unused
  const float* Wq = (const float*)d_in[2];
  const float* bq = (const float*)d_in[3];
  const float* Wk = (const float*)d_in[4];
  const float* bk = (const float*)d_in[5];
  const float* Wv = (const float*)d_in[6];
  const float* bv = (const float*)d_in[7];
  const float* Wo = (const float*)d_in[8];
  const float* bo = (const float*)d_in[9];
  const float* ls = (const float*)d_in[10];
  const float* rp = (const float*)d_in[11];

  char* ws = (char*)d_ws;
  size_t off = 0;
  auto alloc = [&](size_t bytes) { char* p = ws + off; off += (bytes + 255) & ~(size_t)255; return p; };
  ushort_t* xb   = (ushort_t*)alloc((size_t)2048*1024*2);
  ushort_t* Wcat = (ushort_t*)alloc((size_t)3072*1024*2);
  ushort_t* Wob  = (ushort_t*)alloc((size_t)1024*1024*2);
  float*    bcat = (float*)   alloc((size_t)3072*4);
  float*    qkv  = (float*)   alloc((size_t)2048*3072*4);
  ushort_t* phiq = (ushort_t*)alloc((size_t)32*1024*64*2);
  ushort_t* phik = (ushort_t*)alloc((size_t)32*1024*64*2);
  ushort_t* vbT  = (ushort_t*)alloc((size_t)32*64*1024*2);
  ushort_t* hb   = (ushort_t*)alloc((size_t)2048*1024*2);

  convert_kernel<<<2048, 256, 0, stream>>>(x, Wq, Wk, Wv, Wo, bq, bk, bv, xb, Wcat, Wob, bcat);
  gemm_bt<<<16*24, 256, 0, stream>>>(xb, Wcat, bcat, qkv, 2048, 3072, 1024);
  phi_kernel<<<512, 256, 0, stream>>>(qkv, ls, rp, phiq, phik, vbT);
  attn_kernel<<<256, 256, 0, stream>>>(phiq, phik, vbT, hb);
  gemm_bt<<<16*8, 256, 0, stream>>>(hb, Wob, bo, (float*)d_out, 2048, 1024, 1024);
}